// Round 5
// baseline (234.868 us; speedup 1.0000x reference)
//
#include <hip/hip_runtime.h>

// GATLayer on MI355X — round 5.
//   gemm_y (fused qk): Y[o][n] = sum_c wm[o][c] x[c][n] (fp16 out);
//                      o0==0 blocks also accumulate q=(wq.x)*log2e, k=(wk.x)*log2e
//   qmax: per-batch max of q
//   gemm_out: out[o][m] = relu(bm[o] + invZ_m * sum_n Y[o][n]*E[m][n])
//     E[m][n] = 2^(leaky(q_n+k_m) - M_m), M_m = leaky(qmax+k_m) — synthesized
//     DIRECTLY into MFMA A-fragments (no LDS tile, no K-loop barriers);
//     Y B-fragments loaded straight from global (L2-hot via XCD swizzle).
//     Z accumulated per-lane in fp32, shfl-reduced across the 4 lane-groups.

constexpr int B = 32, C = 512, N = 1024, O = 512;
constexpr float L2E = 1.4426950408889634f;

typedef _Float16 half8 __attribute__((ext_vector_type(8)));
typedef _Float16 half4v __attribute__((ext_vector_type(4)));
typedef _Float16 half2v __attribute__((ext_vector_type(2)));
typedef float f32x4 __attribute__((ext_vector_type(4)));

#if __has_builtin(__builtin_amdgcn_exp2f)
#define EXP2(x) __builtin_amdgcn_exp2f(x)
#else
#define EXP2(x) exp2f(x)
#endif

__device__ __forceinline__ half8 cvt8(float4 a, float4 b) {
  half8 h;
  h[0] = (_Float16)a.x; h[1] = (_Float16)a.y; h[2] = (_Float16)a.z; h[3] = (_Float16)a.w;
  h[4] = (_Float16)b.x; h[5] = (_Float16)b.y; h[6] = (_Float16)b.z; h[7] = (_Float16)b.w;
  return h;
}

// ---------------- K1: gemm_y + fused qk ----------------
// Block: 128n x 128o, K=c BK=32. Xs stores c-pairs as half2 words (A-frags are
// ds_read_b32 k-pairs). o0==0 blocks accumulate q,k partials from the fp32
// x values already in registers, LDS-reduced in the epilogue.
__global__ __launch_bounds__(256) void gemm_y_kernel(const float* __restrict__ x,
    const float* __restrict__ wm, const float* __restrict__ wq,
    const float* __restrict__ wk, float* __restrict__ q, float* __restrict__ k,
    _Float16* __restrict__ Yt) {
  __shared__ half2v Xs[16 * 130];                 // (c/2, n): low=even c
  __shared__ __align__(16) _Float16 Ws[128 * 40]; // [o][c] K-major
  int b  = blockIdx.y;
  int n0 = blockIdx.x * 128;
  int o0 = blockIdx.z * 128;
  int t = threadIdx.x;
  int w = t >> 6, l = t & 63;
  int nw = w >> 1, ow = w & 1;
  int lm = l & 15, q8 = (l >> 4) * 8, q4 = (l >> 4) * 4;

  int cp = t >> 4, ng = t & 15;           // Xs staging: rows 2cp,2cp+1, n=ng*8..+7
  int wrow = t >> 2, woff = (t & 3) * 8;  // Ws staging
  bool doqk = (blockIdx.z == 0);
  float aq[8] = {}, ak[8] = {};

  f32x4 acc[4][4] = {};
  for (int c0 = 0; c0 < C; c0 += 32) {
    const float* xr = x + ((size_t)b * C + c0 + 2 * cp) * N + n0 + ng * 8;
    float4 a0 = *(const float4*)(xr);
    float4 a1 = *(const float4*)(xr + 4);
    float4 b0 = *(const float4*)(xr + N);
    float4 b1 = *(const float4*)(xr + N + 4);
    const float* wr = wm + (size_t)(o0 + wrow) * C + c0 + woff;
    float4 w0 = *(const float4*)(wr);
    float4 w1 = *(const float4*)(wr + 4);
    float4 w2 = *(const float4*)(wr + (size_t)64 * C);
    float4 w3 = *(const float4*)(wr + (size_t)64 * C + 4);

    if (doqk) {
      float2 wq2 = *(const float2*)&wq[c0 + 2 * cp];
      float2 wk2 = *(const float2*)&wk[c0 + 2 * cp];
      aq[0] = fmaf(wq2.x, a0.x, fmaf(wq2.y, b0.x, aq[0]));
      aq[1] = fmaf(wq2.x, a0.y, fmaf(wq2.y, b0.y, aq[1]));
      aq[2] = fmaf(wq2.x, a0.z, fmaf(wq2.y, b0.z, aq[2]));
      aq[3] = fmaf(wq2.x, a0.w, fmaf(wq2.y, b0.w, aq[3]));
      aq[4] = fmaf(wq2.x, a1.x, fmaf(wq2.y, b1.x, aq[4]));
      aq[5] = fmaf(wq2.x, a1.y, fmaf(wq2.y, b1.y, aq[5]));
      aq[6] = fmaf(wq2.x, a1.z, fmaf(wq2.y, b1.z, aq[6]));
      aq[7] = fmaf(wq2.x, a1.w, fmaf(wq2.y, b1.w, aq[7]));
      ak[0] = fmaf(wk2.x, a0.x, fmaf(wk2.y, b0.x, ak[0]));
      ak[1] = fmaf(wk2.x, a0.y, fmaf(wk2.y, b0.y, ak[1]));
      ak[2] = fmaf(wk2.x, a0.z, fmaf(wk2.y, b0.z, ak[2]));
      ak[3] = fmaf(wk2.x, a0.w, fmaf(wk2.y, b0.w, ak[3]));
      ak[4] = fmaf(wk2.x, a1.x, fmaf(wk2.y, b1.x, ak[4]));
      ak[5] = fmaf(wk2.x, a1.y, fmaf(wk2.y, b1.y, ak[5]));
      ak[6] = fmaf(wk2.x, a1.z, fmaf(wk2.y, b1.z, ak[6]));
      ak[7] = fmaf(wk2.x, a1.w, fmaf(wk2.y, b1.w, ak[7]));
    }

    __syncthreads();
    {
      half2v* xp = &Xs[cp * 130 + ng * 8];
      xp[0] = half2v{(_Float16)a0.x, (_Float16)b0.x};
      xp[1] = half2v{(_Float16)a0.y, (_Float16)b0.y};
      xp[2] = half2v{(_Float16)a0.z, (_Float16)b0.z};
      xp[3] = half2v{(_Float16)a0.w, (_Float16)b0.w};
      xp[4] = half2v{(_Float16)a1.x, (_Float16)b1.x};
      xp[5] = half2v{(_Float16)a1.y, (_Float16)b1.y};
      xp[6] = half2v{(_Float16)a1.z, (_Float16)b1.z};
      xp[7] = half2v{(_Float16)a1.w, (_Float16)b1.w};
      *(half8*)&Ws[wrow * 40 + woff]        = cvt8(w0, w1);
      *(half8*)&Ws[(wrow + 64) * 40 + woff] = cvt8(w2, w3);
    }
    __syncthreads();

    half8 af[4], bf[4];
#pragma unroll
    for (int i = 0; i < 4; ++i) {
      int nrow = nw * 64 + i * 16 + lm;
#pragma unroll
      for (int jp = 0; jp < 4; ++jp) {
        half2v p = Xs[(q4 + jp) * 130 + nrow];
        af[i][2 * jp]     = p[0];
        af[i][2 * jp + 1] = p[1];
      }
    }
#pragma unroll
    for (int j = 0; j < 4; ++j)
      bf[j] = *(const half8*)&Ws[(ow * 64 + j * 16 + lm) * 40 + q8];
#pragma unroll
    for (int i = 0; i < 4; ++i)
#pragma unroll
      for (int j = 0; j < 4; ++j)
        acc[i][j] = __builtin_amdgcn_mfma_f32_16x16x32_f16(af[i], bf[j], acc[i][j], 0, 0, 0);
  }

#pragma unroll
  for (int i = 0; i < 4; ++i) {
    int n_b = n0 + nw * 64 + i * 16 + (l >> 4) * 4;
#pragma unroll
    for (int j = 0; j < 4; ++j) {
      int o_c = o0 + ow * 64 + j * 16 + lm;
      half4v h;
      h[0] = (_Float16)acc[i][j][0];
      h[1] = (_Float16)acc[i][j][1];
      h[2] = (_Float16)acc[i][j][2];
      h[3] = (_Float16)acc[i][j][3];
      *(half4v*)&Yt[((size_t)b * O + o_c) * N + n_b] = h;
    }
  }

  if (doqk) {
    float* red = (float*)Ws;  // 16 x (stride 132) floats = 8448 B <= 10240 B
    __syncthreads();          // all MFMA fragment reads from Ws done
#pragma unroll
    for (int j = 0; j < 8; ++j) red[cp * 132 + ng * 8 + j] = aq[j];
    __syncthreads();
    if (t < 128) {
      float s = 0.f;
#pragma unroll
      for (int p = 0; p < 16; ++p) s += red[p * 132 + t];
      q[b * N + n0 + t] = L2E * s;
    }
    __syncthreads();
#pragma unroll
    for (int j = 0; j < 8; ++j) red[cp * 132 + ng * 8 + j] = ak[j];
    __syncthreads();
    if (t < 128) {
      float s = 0.f;
#pragma unroll
      for (int p = 0; p < 16; ++p) s += red[p * 132 + t];
      k[b * N + n0 + t] = L2E * s;
    }
  }
}

// ---------------- K2: qmax[b] ----------------
__global__ __launch_bounds__(256) void qmax_kernel(const float* __restrict__ q,
                                                   float* __restrict__ qmax) {
  int b = blockIdx.x;
  int tid = threadIdx.x;
  float m = -1e30f;
  for (int n = tid; n < N; n += 256) m = fmaxf(m, q[b * N + n]);
#pragma unroll
  for (int off = 32; off > 0; off >>= 1) m = fmaxf(m, __shfl_down(m, off, 64));
  __shared__ float red[4];
  if ((tid & 63) == 0) red[tid >> 6] = m;
  __syncthreads();
  if (tid == 0) qmax[b] = fmaxf(fmaxf(red[0], red[1]), fmaxf(red[2], red[3]));
}

// ---------------- K3: gemm_out — barrier-free K-loop ----------------
// Block: 128m (A = synthesized E frags) x 128o (B = Y frags from global), BK=32.
__global__ __launch_bounds__(256) void gemm_out_kernel(const _Float16* __restrict__ Yt,
    const float* __restrict__ q, const float* __restrict__ k,
    const float* __restrict__ qmax, const float* __restrict__ bm,
    float* __restrict__ out) {
  __shared__ __align__(16) float qs[N];
  __shared__ float izs[128];
  int b  = blockIdx.y;
  int o0 = blockIdx.x * 128;
  int m0 = blockIdx.z * 128;
  int t = threadIdx.x;
  int w = t >> 6, l = t & 63;
  int mw = w >> 1, ow = w & 1;
  int lm = l & 15, g = l >> 4, q8 = g * 8;

  *(float4*)&qs[t * 4] = *(const float4*)&q[b * N + t * 4];

  float qmv = qmax[b];
  float k2[4], k3[4];
#pragma unroll
  for (int i = 0; i < 4; ++i) {
    float km = k[b * N + m0 + mw * 64 + i * 16 + lm];
    float s0 = qmv + km;
    float M  = fmaxf(s0, 0.01f * s0);
    k2[i] = km - M;
    k3[i] = fmaf(0.01f, km, -M);
  }
  float Zp[4] = {0.f, 0.f, 0.f, 0.f};
  const _Float16* ybase = Yt + ((size_t)b * O + o0 + ow * 64 + lm) * N + q8;
  __syncthreads();  // qs staged

  f32x4 acc[4][4] = {};
#pragma unroll 2
  for (int n0k = 0; n0k < N; n0k += 32) {
    half8 bf[4];
#pragma unroll
    for (int j = 0; j < 4; ++j)
      bf[j] = *(const half8*)(ybase + (size_t)(j * 16) * N + n0k);
    float4 qa = *(const float4*)&qs[n0k + q8];
    float4 qb = *(const float4*)&qs[n0k + q8 + 4];
    float qv[8] = {qa.x, qa.y, qa.z, qa.w, qb.x, qb.y, qb.z, qb.w};
#pragma unroll
    for (int i = 0; i < 4; ++i) {
      half8 af;
      float zz = 0.f;
#pragma unroll
      for (int jj = 0; jj < 8; ++jj) {
        float arg = fmaxf(qv[jj] + k2[i], fmaf(0.01f, qv[jj], k3[i]));
        float e = EXP2(arg);
        zz += e;
        af[jj] = (_Float16)e;
      }
      Zp[i] += zz;
#pragma unroll
      for (int j = 0; j < 4; ++j)
        acc[i][j] = __builtin_amdgcn_mfma_f32_16x16x32_f16(af, bf[j], acc[i][j], 0, 0, 0);
    }
  }

  // Z: sum across the 4 lane-groups (n-slices), publish invZ per m-row
#pragma unroll
  for (int i = 0; i < 4; ++i) {
    float z = Zp[i];
    z += __shfl_xor(z, 16, 64);
    z += __shfl_xor(z, 32, 64);
    if (ow == 0 && g == 0) izs[mw * 64 + i * 16 + lm] = 1.0f / z;
  }
  __syncthreads();

#pragma unroll
  for (int i = 0; i < 4; ++i) {
    int m_b = m0 + mw * 64 + i * 16 + g * 4;
    float4 iz4 = *(const float4*)&izs[mw * 64 + i * 16 + g * 4];
#pragma unroll
    for (int j = 0; j < 4; ++j) {
      int o_c = o0 + ow * 64 + j * 16 + lm;
      float bias = bm[o_c];
      float4 r;
      r.x = fmaxf(fmaf(acc[i][j][0], iz4.x, bias), 0.f);
      r.y = fmaxf(fmaf(acc[i][j][1], iz4.y, bias), 0.f);
      r.z = fmaxf(fmaf(acc[i][j][2], iz4.z, bias), 0.f);
      r.w = fmaxf(fmaf(acc[i][j][3], iz4.w, bias), 0.f);
      *(float4*)&out[((size_t)b * O + o_c) * N + m_b] = r;
    }
  }
}

extern "C" void kernel_launch(void* const* d_in, const int* in_sizes, int n_in,
                              void* d_out, int out_size, void* d_ws, size_t ws_size,
                              hipStream_t stream) {
  const float* x  = (const float*)d_in[0];
  const float* wq = (const float*)d_in[1];
  const float* wk = (const float*)d_in[2];
  const float* wm = (const float*)d_in[3];
  const float* bm = (const float*)d_in[4];
  float* out = (float*)d_out;

  // ws: q[B*N] | k[B*N] | qmax[64] (f32) | Yt[B*O*N] fp16   (~32.3 MiB)
  float* q    = (float*)d_ws;
  float* k    = q + B * N;
  float* qmax = k + B * N;
  _Float16* Yt = (_Float16*)(qmax + 64);

  // gemm_y: x-strip (per n-tile,b) reused by o-blocks at linear stride 256 (same XCD)
  gemm_y_kernel<<<dim3(N / 128, B, O / 128), 256, 0, stream>>>(x, wm, wq, wk, q, k, Yt);
  qmax_kernel<<<dim3(B), 256, 0, stream>>>(q, qmax);
  // gemm_out: Y-strip (per o-tile,b) reused by m-blocks at linear stride 128 (same XCD)
  gemm_out_kernel<<<dim3(O / 128, B, N / 128), 256, 0, stream>>>(Yt, q, k, qmax, bm, out);
}

// Round 7
// 224.030 us; speedup vs baseline: 1.0484x; 1.0484x over previous
//
#include <hip/hip_runtime.h>

// GATLayer on MI355X — round 7 (bisect: round-5 gemm_y/qmax [known-good] +
// round-6 gemm_out [4-way m-split, Ys in LDS] + Z-from-fp16 consistency).
//   gemm_y (fused qk): Y[o][n] = sum_c wm[o][c] x[c][n] (fp16 out);
//       o0==0 blocks also produce q=(wq.x)*L2E, k=(wk.x)*L2E.
//   qmax_kernel: qmax[b] = max_n q[b][n].
//   gemm_out: out[o][m] = relu(bm[o] + invZ_m * sum_n Y[o][n]*E[m][n])
//       E synthesized into MFMA A-frags (m = lane&15, k = quad*8+j); each wave
//       owns a DISTINCT 32-m strip (E redundancy 4x, was 8x in round 5);
//       Y tile staged in LDS per 32-n slab; Z accumulated from the SAME fp16
//       values fed to the MFMA (numerator/denominator consistent).

constexpr int B = 32, C = 512, N = 1024, O = 512;
constexpr float L2E = 1.4426950408889634f;

typedef _Float16 half8 __attribute__((ext_vector_type(8)));
typedef _Float16 half4v __attribute__((ext_vector_type(4)));
typedef _Float16 half2v __attribute__((ext_vector_type(2)));
typedef float f32x4 __attribute__((ext_vector_type(4)));

#if __has_builtin(__builtin_amdgcn_exp2f)
#define EXP2(x) __builtin_amdgcn_exp2f(x)
#else
#define EXP2(x) exp2f(x)
#endif

__device__ __forceinline__ half8 cvt8(float4 a, float4 b) {
  half8 h;
  h[0] = (_Float16)a.x; h[1] = (_Float16)a.y; h[2] = (_Float16)a.z; h[3] = (_Float16)a.w;
  h[4] = (_Float16)b.x; h[5] = (_Float16)b.y; h[6] = (_Float16)b.z; h[7] = (_Float16)b.w;
  return h;
}

// ---------------- K1: gemm_y + fused qk (round-5 verbatim, known good) -------
__global__ __launch_bounds__(256) void gemm_y_kernel(const float* __restrict__ x,
    const float* __restrict__ wm, const float* __restrict__ wq,
    const float* __restrict__ wk, float* __restrict__ q, float* __restrict__ k,
    _Float16* __restrict__ Yt) {
  __shared__ half2v Xs[16 * 130];                 // (c/2, n): low=even c
  __shared__ __align__(16) _Float16 Ws[128 * 40]; // [o][c] K-major
  int b  = blockIdx.y;
  int n0 = blockIdx.x * 128;
  int o0 = blockIdx.z * 128;
  int t = threadIdx.x;
  int w = t >> 6, l = t & 63;
  int nw = w >> 1, ow = w & 1;
  int lm = l & 15, q8 = (l >> 4) * 8, q4 = (l >> 4) * 4;

  int cp = t >> 4, ng = t & 15;           // Xs staging: rows 2cp,2cp+1, n=ng*8..+7
  int wrow = t >> 2, woff = (t & 3) * 8;  // Ws staging
  bool doqk = (blockIdx.z == 0);
  float aq[8] = {}, ak[8] = {};

  f32x4 acc[4][4] = {};
  for (int c0 = 0; c0 < C; c0 += 32) {
    const float* xr = x + ((size_t)b * C + c0 + 2 * cp) * N + n0 + ng * 8;
    float4 a0 = *(const float4*)(xr);
    float4 a1 = *(const float4*)(xr + 4);
    float4 b0 = *(const float4*)(xr + N);
    float4 b1 = *(const float4*)(xr + N + 4);
    const float* wr = wm + (size_t)(o0 + wrow) * C + c0 + woff;
    float4 w0 = *(const float4*)(wr);
    float4 w1 = *(const float4*)(wr + 4);
    float4 w2 = *(const float4*)(wr + (size_t)64 * C);
    float4 w3 = *(const float4*)(wr + (size_t)64 * C + 4);

    if (doqk) {
      float2 wq2 = *(const float2*)&wq[c0 + 2 * cp];
      float2 wk2 = *(const float2*)&wk[c0 + 2 * cp];
      aq[0] = fmaf(wq2.x, a0.x, fmaf(wq2.y, b0.x, aq[0]));
      aq[1] = fmaf(wq2.x, a0.y, fmaf(wq2.y, b0.y, aq[1]));
      aq[2] = fmaf(wq2.x, a0.z, fmaf(wq2.y, b0.z, aq[2]));
      aq[3] = fmaf(wq2.x, a0.w, fmaf(wq2.y, b0.w, aq[3]));
      aq[4] = fmaf(wq2.x, a1.x, fmaf(wq2.y, b1.x, aq[4]));
      aq[5] = fmaf(wq2.x, a1.y, fmaf(wq2.y, b1.y, aq[5]));
      aq[6] = fmaf(wq2.x, a1.z, fmaf(wq2.y, b1.z, aq[6]));
      aq[7] = fmaf(wq2.x, a1.w, fmaf(wq2.y, b1.w, aq[7]));
      ak[0] = fmaf(wk2.x, a0.x, fmaf(wk2.y, b0.x, ak[0]));
      ak[1] = fmaf(wk2.x, a0.y, fmaf(wk2.y, b0.y, ak[1]));
      ak[2] = fmaf(wk2.x, a0.z, fmaf(wk2.y, b0.z, ak[2]));
      ak[3] = fmaf(wk2.x, a0.w, fmaf(wk2.y, b0.w, ak[3]));
      ak[4] = fmaf(wk2.x, a1.x, fmaf(wk2.y, b1.x, ak[4]));
      ak[5] = fmaf(wk2.x, a1.y, fmaf(wk2.y, b1.y, ak[5]));
      ak[6] = fmaf(wk2.x, a1.z, fmaf(wk2.y, b1.z, ak[6]));
      ak[7] = fmaf(wk2.x, a1.w, fmaf(wk2.y, b1.w, ak[7]));
    }

    __syncthreads();
    {
      half2v* xp = &Xs[cp * 130 + ng * 8];
      xp[0] = half2v{(_Float16)a0.x, (_Float16)b0.x};
      xp[1] = half2v{(_Float16)a0.y, (_Float16)b0.y};
      xp[2] = half2v{(_Float16)a0.z, (_Float16)b0.z};
      xp[3] = half2v{(_Float16)a0.w, (_Float16)b0.w};
      xp[4] = half2v{(_Float16)a1.x, (_Float16)b1.x};
      xp[5] = half2v{(_Float16)a1.y, (_Float16)b1.y};
      xp[6] = half2v{(_Float16)a1.z, (_Float16)b1.z};
      xp[7] = half2v{(_Float16)a1.w, (_Float16)b1.w};
      *(half8*)&Ws[wrow * 40 + woff]        = cvt8(w0, w1);
      *(half8*)&Ws[(wrow + 64) * 40 + woff] = cvt8(w2, w3);
    }
    __syncthreads();

    half8 af[4], bf[4];
#pragma unroll
    for (int i = 0; i < 4; ++i) {
      int nrow = nw * 64 + i * 16 + lm;
#pragma unroll
      for (int jp = 0; jp < 4; ++jp) {
        half2v p = Xs[(q4 + jp) * 130 + nrow];
        af[i][2 * jp]     = p[0];
        af[i][2 * jp + 1] = p[1];
      }
    }
#pragma unroll
    for (int j = 0; j < 4; ++j)
      bf[j] = *(const half8*)&Ws[(ow * 64 + j * 16 + lm) * 40 + q8];
#pragma unroll
    for (int i = 0; i < 4; ++i)
#pragma unroll
      for (int j = 0; j < 4; ++j)
        acc[i][j] = __builtin_amdgcn_mfma_f32_16x16x32_f16(af[i], bf[j], acc[i][j], 0, 0, 0);
  }

#pragma unroll
  for (int i = 0; i < 4; ++i) {
    int n_b = n0 + nw * 64 + i * 16 + (l >> 4) * 4;
#pragma unroll
    for (int j = 0; j < 4; ++j) {
      int o_c = o0 + ow * 64 + j * 16 + lm;
      half4v h;
      h[0] = (_Float16)acc[i][j][0];
      h[1] = (_Float16)acc[i][j][1];
      h[2] = (_Float16)acc[i][j][2];
      h[3] = (_Float16)acc[i][j][3];
      *(half4v*)&Yt[((size_t)b * O + o_c) * N + n_b] = h;
    }
  }

  if (doqk) {
    float* red = (float*)Ws;  // 16 x (stride 132) floats = 8448 B <= 10240 B
    __syncthreads();          // all MFMA fragment reads from Ws done
#pragma unroll
    for (int j = 0; j < 8; ++j) red[cp * 132 + ng * 8 + j] = aq[j];
    __syncthreads();
    if (t < 128) {
      float s = 0.f;
#pragma unroll
      for (int p = 0; p < 16; ++p) s += red[p * 132 + t];
      q[b * N + n0 + t] = L2E * s;
    }
    __syncthreads();
#pragma unroll
    for (int j = 0; j < 8; ++j) red[cp * 132 + ng * 8 + j] = ak[j];
    __syncthreads();
    if (t < 128) {
      float s = 0.f;
#pragma unroll
      for (int p = 0; p < 16; ++p) s += red[p * 132 + t];
      k[b * N + n0 + t] = L2E * s;
    }
  }
}

// ---------------- K2: qmax[b] (round-5 verbatim) ----------------
__global__ __launch_bounds__(256) void qmax_kernel(const float* __restrict__ q,
                                                   float* __restrict__ qmax) {
  int b = blockIdx.x;
  int tid = threadIdx.x;
  float m = -1e30f;
  for (int n = tid; n < N; n += 256) m = fmaxf(m, q[b * N + n]);
#pragma unroll
  for (int off = 32; off > 0; off >>= 1) m = fmaxf(m, __shfl_down(m, off, 64));
  __shared__ float red[4];
  if ((tid & 63) == 0) red[tid >> 6] = m;
  __syncthreads();
  if (tid == 0) qmax[b] = fmaxf(fmaxf(red[0], red[1]), fmaxf(red[2], red[3]));
}

// ---------------- K3: gemm_out (round-6 structure, Z from fp16 E) ------------
// Block 128m x 128o. Wave w owns m-rows [32w,32w+32) (i=0,1), ALL 128 o (j=0..7).
__global__ __launch_bounds__(256) void gemm_out_kernel(const _Float16* __restrict__ Yt,
    const float* __restrict__ q, const float* __restrict__ k,
    const float* __restrict__ qmax, const float* __restrict__ bm,
    float* __restrict__ out) {
  __shared__ __align__(16) float qs[N];
  __shared__ __align__(16) _Float16 Ys[128 * 40];
  __shared__ float izs[128];
  int b  = blockIdx.y;
  int o0 = blockIdx.x * 128;
  int m0 = blockIdx.z * 128;
  int t = threadIdx.x;
  int w = t >> 6, l = t & 63;
  int lm = l & 15, g = l >> 4, q8 = g * 8;

  *(float4*)&qs[t * 4] = *(const float4*)&q[b * N + t * 4];

  float qmv = qmax[b];
  float k2[2], k3[2];
#pragma unroll
  for (int i = 0; i < 2; ++i) {
    float km = k[b * N + m0 + w * 32 + i * 16 + lm];
    float s0 = qmv + km;
    float M  = fmaxf(s0, 0.01f * s0);
    k2[i] = km - M;
    k3[i] = fmaf(0.01f, km, -M);
  }
  float Zp[2] = {0.f, 0.f};
  int yr = t >> 1, yp = t & 1;
  const _Float16* ysrc = Yt + ((size_t)b * O + o0 + yr) * N + yp * 16;
  __syncthreads();  // qs staged

  f32x4 acc[2][8] = {};
  for (int n0k = 0; n0k < N; n0k += 32) {
    half8 y0 = *(const half8*)(ysrc + n0k);
    half8 y1 = *(const half8*)(ysrc + n0k + 8);
    float4 qa = *(const float4*)&qs[n0k + q8];
    float4 qb = *(const float4*)&qs[n0k + q8 + 4];
    float qv[8] = {qa.x, qa.y, qa.z, qa.w, qb.x, qb.y, qb.z, qb.w};
    half8 af[2];
#pragma unroll
    for (int i = 0; i < 2; ++i) {
      float zz = 0.f;
#pragma unroll
      for (int jj = 0; jj < 8; ++jj) {
        float arg = fmaxf(qv[jj] + k2[i], fmaf(0.01f, qv[jj], k3[i]));
        _Float16 eh = (_Float16)EXP2(arg);
        af[i][jj] = eh;
        zz += (float)eh;  // Z from the SAME fp16 values the MFMA consumes
      }
      Zp[i] += zz;
    }
    __syncthreads();  // previous bf reads done
    *(half8*)&Ys[yr * 40 + yp * 16]     = y0;
    *(half8*)&Ys[yr * 40 + yp * 16 + 8] = y1;
    __syncthreads();

    half8 bf[8];
#pragma unroll
    for (int j = 0; j < 8; ++j)
      bf[j] = *(const half8*)&Ys[(j * 16 + lm) * 40 + q8];
#pragma unroll
    for (int i = 0; i < 2; ++i)
#pragma unroll
      for (int j = 0; j < 8; ++j)
        acc[i][j] = __builtin_amdgcn_mfma_f32_16x16x32_f16(af[i], bf[j], acc[i][j], 0, 0, 0);
  }

  // Z across the 4 n-quads (within wave), publish invZ per m-row
#pragma unroll
  for (int i = 0; i < 2; ++i) {
    float z = Zp[i];
    z += __shfl_xor(z, 16, 64);
    z += __shfl_xor(z, 32, 64);
    if (g == 0) izs[w * 32 + i * 16 + lm] = 1.0f / z;
  }
  __syncthreads();

#pragma unroll
  for (int i = 0; i < 2; ++i) {
    int m_b = m0 + w * 32 + i * 16 + g * 4;
    float4 iz4 = *(const float4*)&izs[w * 32 + i * 16 + g * 4];
#pragma unroll
    for (int j = 0; j < 8; ++j) {
      int o_c = o0 + j * 16 + lm;
      float bias = bm[o_c];
      float4 r;
      r.x = fmaxf(fmaf(acc[i][j][0], iz4.x, bias), 0.f);
      r.y = fmaxf(fmaf(acc[i][j][1], iz4.y, bias), 0.f);
      r.z = fmaxf(fmaf(acc[i][j][2], iz4.z, bias), 0.f);
      r.w = fmaxf(fmaf(acc[i][j][3], iz4.w, bias), 0.f);
      *(float4*)&out[((size_t)b * O + o_c) * N + m_b] = r;
    }
  }
}

extern "C" void kernel_launch(void* const* d_in, const int* in_sizes, int n_in,
                              void* d_out, int out_size, void* d_ws, size_t ws_size,
                              hipStream_t stream) {
  const float* x  = (const float*)d_in[0];
  const float* wq = (const float*)d_in[1];
  const float* wk = (const float*)d_in[2];
  const float* wm = (const float*)d_in[3];
  const float* bm = (const float*)d_in[4];
  float* out = (float*)d_out;

  // ws: q[B*N] | k[B*N] | qmax[64] (f32) | Yt[B*O*N] fp16   (~32.3 MiB)
  float* q    = (float*)d_ws;
  float* k    = q + B * N;
  float* qmax = k + B * N;
  _Float16* Yt = (_Float16*)(qmax + 64);

  // gemm_y: x-strip (n-tile,b) reused by o-blocks at linear stride 256 (same XCD)
  gemm_y_kernel<<<dim3(N / 128, B, O / 128), 256, 0, stream>>>(x, wm, wq, wk, q, k, Yt);
  qmax_kernel<<<dim3(B), 256, 0, stream>>>(q, qmax);
  // gemm_out: Y-strip (o-tile,b) reused by m-blocks at linear stride 128 (same XCD)
  gemm_out_kernel<<<dim3(O / 128, B, N / 128), 256, 0, stream>>>(Yt, q, k, qmax, bm, out);
}